// Round 9
// baseline (254.920 us; speedup 1.0000x reference)
//
#include <hip/hip_runtime.h>

// R16: MEASUREMENT ROUND — two-point REP scaling of the R14 body.
// R15 post-mortem: warming L3 (50MB prefetch, +9us) changed the main
// kernel's time by ZERO -> not memory service. All visible pipes <25%,
// warm==cold, structure-invariant ~30us body across 7 rewrites. The one
// unseparated hypothesis: per-dispatch FIXED cost f (launch/ramp/drain).
// dur(REP) = REP*b + f. Probe launched at REP=1 and REP=4 (same kernel,
// runtime rep loop, memory-clobber per rep to defeat CSE); REP=4 lands
// ~75-115us > 42us fills -> first direct rocprof counters for the real
// body. Final dispatch = R14 verbatim (correctness; probes' outputs are
// overwritten). Decode next round:
//   dur4 = top-5 row;  dur1 = score - 111 - 30 - dur4;
//   b = (dur4-dur1)/3;  f = dur1 - b.

#define BDIM 64

__device__ __forceinline__ void gld16(const void* g, void* l) {
    __builtin_amdgcn_global_load_lds((__attribute__((address_space(1))) void*)g,
                                     (__attribute__((address_space(3))) void*)l,
                                     16, 0, 0);
}

// ---------------- R14 body as a macro-free inline (shared) ----------------
// (kept byte-for-byte equivalent in structure to R14's kernel body)

template<bool PROBE>
__device__ __forceinline__ void mlp_body(
    const float* __restrict__ cont_p, const float* __restrict__ cont_c,
    const int* __restrict__ cat_p, const int* __restrict__ cat_c,
    const int* __restrict__ lengths,
    const float* __restrict__ w_p1, const float* __restrict__ b_p1,
    const float* __restrict__ w_p2, const float* __restrict__ b_p2,
    const float* __restrict__ w_c1, const float* __restrict__ b_c1,
    const float* __restrict__ w_c2, const float* __restrict__ b_c2,
    const float* __restrict__ emb_g,  const float* __restrict__ emb_k,
    const float* __restrict__ emb_pr, const float* __restrict__ emb_j,
    const float* __restrict__ emb_r,  const float* __restrict__ emb_pl,
    const float* __restrict__ emb_a,
    const float* __restrict__ w_fc1, const float* __restrict__ b_fc1,
    const float* __restrict__ w_fc2, const float* __restrict__ b_fc2,
    float* __restrict__ out,
    float* sBuf, int lane, int b)
{
    constexpr int S = 256;
    float* sPc  = sBuf;
    float* sCc  = sBuf + 768;
    int*   sKp  = (int*)(sBuf + 1280);
    int*   hist = (int*)sBuf;
    float* sAcc = sBuf + 768;
    float* sPool = sBuf + 832;

    const int ch = lane & 31, h = lane >> 5;

    int L = lengths[b]; L = (L < 1) ? 1 : (L > S ? S : L);
    const float Lf = (float)L, invL = 1.0f / Lf;

    // ---- staging: global_load_lds 16B, wave-uniform chunk gating ----
    {
        const char* gp = (const char*)(cont_p + (size_t)b * 768);
        const char* gc = (const char*)(cont_c + (size_t)b * 512);
        const char* gk = (const char*)(cat_p + (size_t)b * 1280);
        const int lo = 16 * lane;
        const int bP = 12 * L, bC = 8 * L, bK = 20 * L;
        gld16(gp + lo, (char*)sPc);
        if (1024 < bP) gld16(gp + 1024 + lo, (char*)sPc + 1024);
        if (2048 < bP) gld16(gp + 2048 + lo, (char*)sPc + 2048);
        gld16(gc + lo, (char*)sCc);
        if (1024 < bC) gld16(gc + 1024 + lo, (char*)sCc + 1024);
        #pragma unroll
        for (int j = 0; j < 5; ++j)
            if (1024 * j < bK) gld16(gk + 1024 * j + lo, (char*)sKp + 1024 * j);
    }
    const int limc = 2 * L;
    const int4* KC = (const int4*)(cat_c + (size_t)b * 512);
    int4 qc0, qc1;
    const bool hc0 = (4 * lane < limc), hc1 = (256 + 4 * lane < limc);
    if (hc0) qc0 = KC[lane];
    if (hc1) qc1 = KC[lane + 64];

    const float wp0 = w_p1[ch], wp1 = w_p1[32 + ch], wp2 = w_p1[64 + ch], bp = b_p1[ch];
    const float wc0 = w_c1[ch], wc1 = w_c1[32 + ch], bc = b_c1[ch];
    const float eg0 = emb_g[ch],  eg1 = emb_g[32 + ch];
    const float ek0 = emb_k[ch],  ek1 = emb_k[32 + ch];
    const float er0 = emb_pr[ch], er1 = emb_pr[32 + ch];
    const float bias2 = h ? b_c2[ch] : b_p2[ch];
    const float bf1 = b_fc1[lane];
    const float2 wf2 = *(const float2*)&w_fc2[2 * lane];
    const float bq0 = b_fc2[0], bq1 = b_fc2[1];

    __syncthreads();   // B1: vmcnt drain -> all staged data in LDS

    // ---- token relu-MLP: contiguous half-wave split of 4-token groups ----
    float aP = 0.f, aC = 0.f;
    {
        const int gf = L >> 2;
        const int gh = (gf + 1) >> 1;
        const float4* tp4 = (const float4*)sPc;
        const float4* tc4 = (const float4*)sCc;
        #pragma unroll 4
        for (int i = 0; i < gh; ++i) {
            const int g = h ? gh + i : i;
            if (g < gf) {
                float4 a  = tp4[3 * g], bb = tp4[3 * g + 1], cc = tp4[3 * g + 2];
                float4 d  = tc4[2 * g], ee = tc4[2 * g + 1];
                float p0 = fmaxf(fmaf(a.x,  wp0, fmaf(a.y,  wp1, fmaf(a.z,  wp2, bp))), 0.f);
                float p1 = fmaxf(fmaf(a.w,  wp0, fmaf(bb.x, wp1, fmaf(bb.y, wp2, bp))), 0.f);
                float p2 = fmaxf(fmaf(bb.z, wp0, fmaf(bb.w, wp1, fmaf(cc.x, wp2, bp))), 0.f);
                float p3 = fmaxf(fmaf(cc.y, wp0, fmaf(cc.z, wp1, fmaf(cc.w, wp2, bp))), 0.f);
                aP += (p0 + p1) + (p2 + p3);
                float q0 = fmaxf(fmaf(d.x,  wc0, fmaf(d.y,  wc1, bc)), 0.f);
                float q1 = fmaxf(fmaf(d.z,  wc0, fmaf(d.w,  wc1, bc)), 0.f);
                float q2 = fmaxf(fmaf(ee.x, wc0, fmaf(ee.y, wc1, bc)), 0.f);
                float q3 = fmaxf(fmaf(ee.z, wc0, fmaf(ee.w, wc1, bc)), 0.f);
                aC += (q0 + q1) + (q2 + q3);
            }
        }
        const int rem = L & 3;
        if (h == 0 && rem) {
            const float* tp = sPc + 12 * gf;
            const float* tc = sCc + 8 * gf;
            for (int r = 0; r < rem; ++r) {
                aP += fmaxf(fmaf(tp[3*r], wp0, fmaf(tp[3*r+1], wp1, fmaf(tp[3*r+2], wp2, bp))), 0.f);
                aC += fmaxf(fmaf(tc[2*r], wc0, fmaf(tc[2*r+1], wc1, bc)), 0.f);
            }
        }
        aP += __shfl_xor(aP, 32);
        aC += __shfl_xor(aC, 32);
        sAcc[lane] = (h ? aC : aP) * invL;
    }
    __syncthreads();   // B2: fence -> hist may overwrite cont_p region

    hist[lane] = 0;
    if (lane < 32) hist[64 + lane] = 0;

    int sg = 0, sk = 0, sp = 0;
    {
        const int limp = 5 * L;
        const int m0 = (lane << 2) % 5;
        #pragma unroll
        for (int j = 0; j < 5; ++j) {
            if (256 * j < limp) {
                int4 v4 = ((const int4*)sKp)[lane + 64 * j];
                const int base = 4 * lane + 256 * j;
                int mj = m0 + j; if (mj >= 5) mj -= 5;
                const int v[4] = {v4.x, v4.y, v4.z, v4.w};
                #pragma unroll
                for (int c = 0; c < 4; ++c) {
                    int f = mj + c; if (f >= 5) f -= 5;
                    const bool val = (base + c) < limp;
                    const int vv = v[c];
                    sg += (val && f == 0) ? vv : 0;
                    sk += (val && f == 1) ? vv : 0;
                    sp += (val && f == 2) ? vv : 0;
                    if (val && f >= 3) atomicAdd(&hist[(f == 4 ? 11 : 0) + vv], 1);
                }
            }
        }
        if (hc0) {
            atomicAdd(&hist[45 + qc0.x], 1);
            if (4 * lane + 1 < limc) atomicAdd(&hist[64 + qc0.y], 1);
            if (4 * lane + 2 < limc) atomicAdd(&hist[45 + qc0.z], 1);
            if (4 * lane + 3 < limc) atomicAdd(&hist[64 + qc0.w], 1);
        }
        if (hc1) {
            atomicAdd(&hist[45 + qc1.x], 1);
            if (257 + 4 * lane < limc) atomicAdd(&hist[64 + qc1.y], 1);
            if (258 + 4 * lane < limc) atomicAdd(&hist[45 + qc1.z], 1);
            if (259 + 4 * lane < limc) atomicAdd(&hist[64 + qc1.w], 1);
        }
    }
    #pragma unroll
    for (int d = 32; d; d >>= 1) {
        sg += __shfl_xor(sg, d); sk += __shfl_xor(sk, d); sp += __shfl_xor(sp, d);
    }

    float A;
    {
        float fg = (float)sg, fk = (float)sk, fp = (float)sp;
        A = fmaf(Lf - fg, eg0, fg * eg1) + fmaf(Lf - fk, ek0, fk * ek1)
          + fmaf(Lf - fp, er0, fp * er1);
        A = h ? 0.f : A;
    }
    {
        const float* tA = h ? emb_pl : emb_j;
        const float* tB = h ? emb_a  : emb_r;
        const int nA = h ? 19 : 11;
        const int nT = h ? 50 : 45;
        const int hb = h ? 45 : 0;
        #pragma unroll 5
        for (int r = 0; r < nT; ++r) {
            const float* p = (r < nA) ? (tA + (r << 5)) : (tB + ((r - nA) << 5));
            A = fmaf((float)hist[hb + r], p[ch], A);
        }
        sPool[(h << 5) + ch] = A * (invL * (h ? 0.5f : 0.2f));
    }
    {
        const float* W2 = h ? w_c2 : w_p2;
        const float* acc = sAcc + (h << 5);
        float v = bias2;
        #pragma unroll 8
        for (int k = 0; k < 32; ++k)
            v = fmaf(acc[k], W2[(k << 5) + ch], v);
        sPool[64 + (h << 5) + ch] = v;
    }

    {
        float x = bf1, y = 0.f;
        #pragma unroll 8
        for (int k = 0; k < 128; k += 2) {
            float w0 = w_fc1[(size_t)k * 64 + lane];
            float w1 = w_fc1[(size_t)(k + 1) * 64 + lane];
            float2 u = *(const float2*)&sPool[k];
            x = fmaf(u.x, w0, x); y = fmaf(u.y, w1, y);
        }
        float hv = fmaxf(x + y, 0.f);
        float q0 = hv * wf2.x, q1 = hv * wf2.y;
        #pragma unroll
        for (int d = 32; d; d >>= 1) {
            q0 += __shfl_xor(q0, d); q1 += __shfl_xor(q1, d);
        }
        if (lane == 0) {
            float2 o2;
            o2.x = fmaxf(q0 + bq0, 0.f);
            o2.y = fmaxf(q1 + bq1, 0.f);
            *(float2*)&out[(size_t)b * 2] = o2;
        }
    }
}

// ---------------- probe: body x rep (runtime), CSE-defeated ----------------
__global__ __launch_bounds__(BDIM)
void mlp_probe(const float* __restrict__ cont_p, const float* __restrict__ cont_c,
               const int* __restrict__ cat_p, const int* __restrict__ cat_c,
               const int* __restrict__ lengths,
               const float* __restrict__ w_p1, const float* __restrict__ b_p1,
               const float* __restrict__ w_p2, const float* __restrict__ b_p2,
               const float* __restrict__ w_c1, const float* __restrict__ b_c1,
               const float* __restrict__ w_c2, const float* __restrict__ b_c2,
               const float* __restrict__ emb_g,  const float* __restrict__ emb_k,
               const float* __restrict__ emb_pr, const float* __restrict__ emb_j,
               const float* __restrict__ emb_r,  const float* __restrict__ emb_pl,
               const float* __restrict__ emb_a,
               const float* __restrict__ w_fc1, const float* __restrict__ b_fc1,
               const float* __restrict__ w_fc2, const float* __restrict__ b_fc2,
               float* __restrict__ out, int rep)
{
    __shared__ __align__(16) float sBuf[2560];
    const int lane = threadIdx.x;
    const int b = blockIdx.x;
    for (int r = 0; r < rep; ++r) {
        asm volatile("" ::: "memory");   // force per-rep reloads (no CSE)
        mlp_body<true>(cont_p, cont_c, cat_p, cat_c, lengths,
                       w_p1, b_p1, w_p2, b_p2, w_c1, b_c1, w_c2, b_c2,
                       emb_g, emb_k, emb_pr, emb_j, emb_r, emb_pl, emb_a,
                       w_fc1, b_fc1, w_fc2, b_fc2, out, sBuf, lane, b);
        __syncthreads();
    }
}

// ---------------- final correctness kernel: R14 verbatim ----------------
__global__ __launch_bounds__(BDIM)
void mlpreg_kernel(const float* __restrict__ cont_p, const float* __restrict__ cont_c,
                   const int* __restrict__ cat_p, const int* __restrict__ cat_c,
                   const int* __restrict__ lengths,
                   const float* __restrict__ w_p1, const float* __restrict__ b_p1,
                   const float* __restrict__ w_p2, const float* __restrict__ b_p2,
                   const float* __restrict__ w_c1, const float* __restrict__ b_c1,
                   const float* __restrict__ w_c2, const float* __restrict__ b_c2,
                   const float* __restrict__ emb_g,  const float* __restrict__ emb_k,
                   const float* __restrict__ emb_pr, const float* __restrict__ emb_j,
                   const float* __restrict__ emb_r,  const float* __restrict__ emb_pl,
                   const float* __restrict__ emb_a,
                   const float* __restrict__ w_fc1, const float* __restrict__ b_fc1,
                   const float* __restrict__ w_fc2, const float* __restrict__ b_fc2,
                   float* __restrict__ out)
{
    __shared__ __align__(16) float sBuf[2560];
    mlp_body<false>(cont_p, cont_c, cat_p, cat_c, lengths,
                    w_p1, b_p1, w_p2, b_p2, w_c1, b_c1, w_c2, b_c2,
                    emb_g, emb_k, emb_pr, emb_j, emb_r, emb_pl, emb_a,
                    w_fc1, b_fc1, w_fc2, b_fc2, out,
                    sBuf, (int)threadIdx.x, (int)blockIdx.x);
}

extern "C" void kernel_launch(void* const* d_in, const int* in_sizes, int n_in,
                              void* d_out, int out_size, void* d_ws, size_t ws_size,
                              hipStream_t stream) {
    const float* cont_p = (const float*)d_in[0];
    const float* cont_c = (const float*)d_in[1];
    const int*   cat_p  = (const int*)d_in[2];
    const int*   cat_c  = (const int*)d_in[3];
    const int*   lens   = (const int*)d_in[4];
    const float* w_p1   = (const float*)d_in[5];
    const float* b_p1   = (const float*)d_in[6];
    const float* w_p2   = (const float*)d_in[7];
    const float* b_p2   = (const float*)d_in[8];
    const float* w_c1   = (const float*)d_in[9];
    const float* b_c1   = (const float*)d_in[10];
    const float* w_c2   = (const float*)d_in[11];
    const float* b_c2   = (const float*)d_in[12];
    const float* emb_g  = (const float*)d_in[13];
    const float* emb_k  = (const float*)d_in[14];
    const float* emb_pr = (const float*)d_in[15];
    const float* emb_j  = (const float*)d_in[16];
    const float* emb_r  = (const float*)d_in[17];
    const float* emb_pl = (const float*)d_in[18];
    const float* emb_a  = (const float*)d_in[19];
    const float* w_fc1  = (const float*)d_in[20];
    const float* b_fc1  = (const float*)d_in[21];
    const float* w_fc2  = (const float*)d_in[22];
    const float* b_fc2  = (const float*)d_in[23];
    float* out = (float*)d_out;

    // probe at REP=1 and REP=4 (durations: dur1 invisible -> from score;
    // dur4 visible in top-5 with counters). Final kernel overwrites out.
    hipLaunchKernelGGL(mlp_probe, dim3(4096), dim3(BDIM), 0, stream,
                       cont_p, cont_c, cat_p, cat_c, lens,
                       w_p1, b_p1, w_p2, b_p2, w_c1, b_c1, w_c2, b_c2,
                       emb_g, emb_k, emb_pr, emb_j, emb_r, emb_pl, emb_a,
                       w_fc1, b_fc1, w_fc2, b_fc2, out, 1);
    hipLaunchKernelGGL(mlp_probe, dim3(4096), dim3(BDIM), 0, stream,
                       cont_p, cont_c, cat_p, cat_c, lens,
                       w_p1, b_p1, w_p2, b_p2, w_c1, b_c1, w_c2, b_c2,
                       emb_g, emb_k, emb_pr, emb_j, emb_r, emb_pl, emb_a,
                       w_fc1, b_fc1, w_fc2, b_fc2, out, 4);
    hipLaunchKernelGGL(mlpreg_kernel, dim3(4096), dim3(BDIM), 0, stream,
                       cont_p, cont_c, cat_p, cat_c, lens,
                       w_p1, b_p1, w_p2, b_p2, w_c1, b_c1, w_c2, b_c2,
                       emb_g, emb_k, emb_pr, emb_j, emb_r, emb_pl, emb_a,
                       w_fc1, b_fc1, w_fc2, b_fc2, out);
}

// Round 10
// 146.579 us; speedup vs baseline: 1.7391x; 1.7391x over previous
//
#include <hip/hip_runtime.h>

// R17: INTRA-WG WORK BALANCING — 4 waves per row, 64-token slab per wave.
// R16 probe decode: warm body ~24us/rep with FETCH~0 (real execution, not
// launch: f~5us; not memory: R15), VALUBusy 42%, time-avg occupancy only
// ~6/32 waves/CU despite 16 WGs/CU launched. Lengths uniform[1,256] ->
// short-L WGs retire early; kernel duration = L~256 straggler rows running
// nearly alone, serial + latency-exposed. Every prior round changed the
// memory plan / op count but never the imbalance. Fix: the pooled sums,
// histograms and index-sums are token-decomposable -> each of 4 waves
// computes slab-partials (R14 token loop on its own gld16-staged slab;
// lane-per-token cat with shared hist atomics); wave 0 runs R14's tail on
// the combined partials. Straggler's dominant phase /4. No cross-WG
// combine, no extra dispatch. LDS 12.2KB -> 8 WGs/CU (wave-cap).
// Algebra unchanged: histogram-weighted table sums, binary-vocab counts =
// index sums, pooling commutes with the 32x32 second layers.

#define BDIM 256

__device__ __forceinline__ void gld16(const void* g, void* l) {
    __builtin_amdgcn_global_load_lds((__attribute__((address_space(1))) void*)g,
                                     (__attribute__((address_space(3))) void*)l,
                                     16, 0, 0);
}

__global__ __launch_bounds__(BDIM)
void mlpreg_kernel(const float* __restrict__ cont_p,
                   const float* __restrict__ cont_c,
                   const int* __restrict__ cat_p,
                   const int* __restrict__ cat_c,
                   const int* __restrict__ lengths,
                   const float* __restrict__ w_p1, const float* __restrict__ b_p1,
                   const float* __restrict__ w_p2, const float* __restrict__ b_p2,
                   const float* __restrict__ w_c1, const float* __restrict__ b_c1,
                   const float* __restrict__ w_c2, const float* __restrict__ b_c2,
                   const float* __restrict__ emb_g,  const float* __restrict__ emb_k,
                   const float* __restrict__ emb_pr, const float* __restrict__ emb_j,
                   const float* __restrict__ emb_r,  const float* __restrict__ emb_pl,
                   const float* __restrict__ emb_a,
                   const float* __restrict__ w_fc1, const float* __restrict__ b_fc1,
                   const float* __restrict__ w_fc2, const float* __restrict__ b_fc2,
                   float* __restrict__ out)
{
    constexpr int S = 256;
    __shared__ __align__(16) float sPc[4][192];   // 3072 B  slab cont_p
    __shared__ __align__(16) float sCc[4][128];   // 2048 B  slab cont_c
    __shared__ __align__(16) int   sKp[4][320];   // 5120 B  slab cat_p
    __shared__ int   hist[96];                    //  384 B  shared (atomics)
    __shared__ float sAccW[4][64];                // 1024 B  per-wave partials
    __shared__ int   sSums[4][3];                 //   48 B
    __shared__ float sPool[128];                  //  512 B
    // ~12.2 KB -> 8 WGs/CU (32-wave cap)

    const int tid  = threadIdx.x;
    const int wid  = tid >> 6;
    const int lane = tid & 63;
    const int ch   = lane & 31, h = lane >> 5;
    const int b    = blockIdx.x;

    int L = lengths[b]; L = (L < 1) ? 1 : (L > S ? S : L);
    const float Lf = (float)L, invL = 1.0f / Lf;

    const int t0 = wid << 6;
    const int nt = (L - t0 < 64) ? (L - t0) : 64;   // may be <= 0

    if (tid < 96) hist[tid] = 0;

    // ---- staging: each wave stages its own slab (exec-masked gld16) ----
    if (nt > 0) {
        const char* gp = (const char*)(cont_p + (size_t)b * 768  + t0 * 3);
        const char* gc = (const char*)(cont_c + (size_t)b * 512  + t0 * 2);
        const char* gk = (const char*)(cat_p  + (size_t)b * 1280 + t0 * 5);
        const int lo = 16 * lane;
        const int bP = 12 * nt, bC = 8 * nt, bK = 20 * nt;
        if (lo < bP)        gld16(gp + lo,        (char*)sPc[wid]);
        if (lo < bC)        gld16(gc + lo,        (char*)sCc[wid]);
        if (lo < bK)        gld16(gk + lo,        (char*)sKp[wid]);
        if (1024 + lo < bK) gld16(gk + 1024 + lo, (char*)sKp[wid] + 1024);
    }
    // cat_c: one token per lane, int2 register load (coalesced)
    int2 qc; qc.x = 0; qc.y = 0;
    if (lane < nt) qc = ((const int2*)(cat_c + (size_t)b * 512))[t0 + lane];

    // ---- first-layer weights (all waves) ----
    const float wp0 = w_p1[ch], wp1v = w_p1[32 + ch], wp2v = w_p1[64 + ch], bp = b_p1[ch];
    const float wc0 = w_c1[ch], wc1v = w_c1[32 + ch], bc = b_c1[ch];
    // ---- tail-only preloads (wave 0; issued early to hide latency) ----
    float eg0 = 0, eg1 = 0, ek0 = 0, ek1 = 0, er0 = 0, er1 = 0;
    float bias2 = 0, bf1 = 0, bq0 = 0, bq1 = 0;
    float2 wf2; wf2.x = 0; wf2.y = 0;
    if (wid == 0) {
        eg0 = emb_g[ch];  eg1 = emb_g[32 + ch];
        ek0 = emb_k[ch];  ek1 = emb_k[32 + ch];
        er0 = emb_pr[ch]; er1 = emb_pr[32 + ch];
        bias2 = h ? b_c2[ch] : b_p2[ch];
        bf1 = b_fc1[lane];
        wf2 = *(const float2*)&w_fc2[2 * lane];
        bq0 = b_fc2[0]; bq1 = b_fc2[1];
    }

    __syncthreads();   // B1: vmcnt drain (slab data in LDS) + hist zeroed

    // ---- token relu-MLP on own slab: channel-per-lane, half-wave split ----
    float aP = 0.f, aC = 0.f;
    if (nt > 0) {
        const int gf = nt >> 2;
        const int gh = (gf + 1) >> 1;
        const float4* tp4 = (const float4*)sPc[wid];
        const float4* tc4 = (const float4*)sCc[wid];
        #pragma unroll 4
        for (int i = 0; i < gh; ++i) {
            const int g = h ? gh + i : i;
            if (g < gf) {
                float4 a  = tp4[3 * g], bb = tp4[3 * g + 1], cc = tp4[3 * g + 2];
                float4 d  = tc4[2 * g], ee = tc4[2 * g + 1];
                float p0 = fmaxf(fmaf(a.x,  wp0, fmaf(a.y,  wp1v, fmaf(a.z,  wp2v, bp))), 0.f);
                float p1 = fmaxf(fmaf(a.w,  wp0, fmaf(bb.x, wp1v, fmaf(bb.y, wp2v, bp))), 0.f);
                float p2 = fmaxf(fmaf(bb.z, wp0, fmaf(bb.w, wp1v, fmaf(cc.x, wp2v, bp))), 0.f);
                float p3 = fmaxf(fmaf(cc.y, wp0, fmaf(cc.z, wp1v, fmaf(cc.w, wp2v, bp))), 0.f);
                aP += (p0 + p1) + (p2 + p3);
                float q0 = fmaxf(fmaf(d.x,  wc0, fmaf(d.y,  wc1v, bc)), 0.f);
                float q1 = fmaxf(fmaf(d.z,  wc0, fmaf(d.w,  wc1v, bc)), 0.f);
                float q2 = fmaxf(fmaf(ee.x, wc0, fmaf(ee.y, wc1v, bc)), 0.f);
                float q3 = fmaxf(fmaf(ee.z, wc0, fmaf(ee.w, wc1v, bc)), 0.f);
                aC += (q0 + q1) + (q2 + q3);
            }
        }
        const int rem = nt & 3;
        if (h == 0 && rem) {
            const float* tp = sPc[wid] + 12 * gf;
            const float* tc = sCc[wid] + 8 * gf;
            for (int r = 0; r < rem; ++r) {
                aP += fmaxf(fmaf(tp[3*r], wp0, fmaf(tp[3*r+1], wp1v, fmaf(tp[3*r+2], wp2v, bp))), 0.f);
                aC += fmaxf(fmaf(tc[2*r], wc0, fmaf(tc[2*r+1], wc1v, bc)), 0.f);
            }
        }
    }
    aP += __shfl_xor(aP, 32);
    aC += __shfl_xor(aC, 32);
    sAccW[wid][lane] = h ? aC : aP;   // un-normalized slab partial

    // ---- cat pass: one token per lane from LDS; shared hist atomics ----
    int v0 = 0, v1 = 0, v2 = 0;
    if (lane < nt) {
        const int* kp = sKp[wid] + 5 * lane;
        v0 = kp[0]; v1 = kp[1]; v2 = kp[2];
        const int v3 = kp[3], v4 = kp[4];
        atomicAdd(&hist[v3], 1);
        atomicAdd(&hist[11 + v4], 1);
        atomicAdd(&hist[45 + qc.x], 1);
        atomicAdd(&hist[64 + qc.y], 1);
    }
    #pragma unroll
    for (int d = 32; d; d >>= 1) {
        v0 += __shfl_xor(v0, d); v1 += __shfl_xor(v1, d); v2 += __shfl_xor(v2, d);
    }
    if (lane == 0) { sSums[wid][0] = v0; sSums[wid][1] = v1; sSums[wid][2] = v2; }
    __syncthreads();   // B2: partials + hist complete

    // ---- tail part 1 (wave 0): closed form + emb hist + 32x32 layers ----
    if (wid == 0) {
        const int sg = sSums[0][0] + sSums[1][0] + sSums[2][0] + sSums[3][0];
        const int sk = sSums[0][1] + sSums[1][1] + sSums[2][1] + sSums[3][1];
        const int sp = sSums[0][2] + sSums[1][2] + sSums[2][2] + sSums[3][2];
        float A;
        {
            float fg = (float)sg, fk = (float)sk, fp = (float)sp;
            A = fmaf(Lf - fg, eg0, fg * eg1) + fmaf(Lf - fk, ek0, fk * ek1)
              + fmaf(Lf - fp, er0, fp * er1);
            A = h ? 0.f : A;
        }
        {
            // h=0: job(11)+rep(34) over hist[0..44]; h=1: place(19)+add(31) over hist[45..94]
            const float* tA = h ? emb_pl : emb_j;
            const float* tB = h ? emb_a  : emb_r;
            const int nA = h ? 19 : 11;
            const int nT = h ? 50 : 45;
            const int hb = h ? 45 : 0;
            #pragma unroll 5
            for (int r = 0; r < nT; ++r) {
                const float* p = (r < nA) ? (tA + (r << 5)) : (tB + ((r - nA) << 5));
                A = fmaf((float)hist[hb + r], p[ch], A);
            }
            sPool[(h << 5) + ch] = A * (invL * (h ? 0.5f : 0.2f));
        }
        {
            // unified 32x32 second layer on summed partials (invL folded out)
            const float* W2 = h ? w_c2 : w_p2;
            float vsum = 0.f;
            #pragma unroll 8
            for (int k = 0; k < 32; ++k) {
                const int a = (h << 5) + k;
                float ak = ((sAccW[0][a] + sAccW[1][a]) + (sAccW[2][a] + sAccW[3][a]));
                vsum = fmaf(ak, W2[(k << 5) + ch], vsum);
            }
            sPool[64 + (h << 5) + ch] = fmaf(invL, vsum, bias2);
        }
    }
    __syncthreads();   // B3: sPool ready (all waves participate, then 1-3 exit)

    // ---- fc1 (one output per lane) + fc2 butterfly (wave 0) ----
    if (wid == 0) {
        float x = bf1, y = 0.f;
        #pragma unroll 8
        for (int k = 0; k < 128; k += 2) {
            float w0 = w_fc1[(size_t)k * 64 + lane];
            float w1 = w_fc1[(size_t)(k + 1) * 64 + lane];
            float2 u = *(const float2*)&sPool[k];
            x = fmaf(u.x, w0, x); y = fmaf(u.y, w1, y);
        }
        float hv = fmaxf(x + y, 0.f);
        float q0 = hv * wf2.x, q1 = hv * wf2.y;
        #pragma unroll
        for (int d = 32; d; d >>= 1) {
            q0 += __shfl_xor(q0, d); q1 += __shfl_xor(q1, d);
        }
        if (lane == 0) {
            float2 o2;
            o2.x = fmaxf(q0 + bq0, 0.f);
            o2.y = fmaxf(q1 + bq1, 0.f);
            *(float2*)&out[(size_t)b * 2] = o2;   // 8B-aligned per-row store
        }
    }
}

extern "C" void kernel_launch(void* const* d_in, const int* in_sizes, int n_in,
                              void* d_out, int out_size, void* d_ws, size_t ws_size,
                              hipStream_t stream) {
    const float* cont_p = (const float*)d_in[0];
    const float* cont_c = (const float*)d_in[1];
    const int*   cat_p  = (const int*)d_in[2];
    const int*   cat_c  = (const int*)d_in[3];
    const int*   lens   = (const int*)d_in[4];
    const float* w_p1   = (const float*)d_in[5];
    const float* b_p1   = (const float*)d_in[6];
    const float* w_p2   = (const float*)d_in[7];
    const float* b_p2   = (const float*)d_in[8];
    const float* w_c1   = (const float*)d_in[9];
    const float* b_c1   = (const float*)d_in[10];
    const float* w_c2   = (const float*)d_in[11];
    const float* b_c2   = (const float*)d_in[12];
    const float* emb_g  = (const float*)d_in[13];
    const float* emb_k  = (const float*)d_in[14];
    const float* emb_pr = (const float*)d_in[15];
    const float* emb_j  = (const float*)d_in[16];
    const float* emb_r  = (const float*)d_in[17];
    const float* emb_pl = (const float*)d_in[18];
    const float* emb_a  = (const float*)d_in[19];
    const float* w_fc1  = (const float*)d_in[20];
    const float* b_fc1  = (const float*)d_in[21];
    const float* w_fc2  = (const float*)d_in[22];
    const float* b_fc2  = (const float*)d_in[23];
    float* out = (float*)d_out;

    hipLaunchKernelGGL(mlpreg_kernel, dim3(4096), dim3(BDIM), 0, stream,
                       cont_p, cont_c, cat_p, cat_c, lens,
                       w_p1, b_p1, w_p2, b_p2, w_c1, b_c1, w_c2, b_c2,
                       emb_g, emb_k, emb_pr, emb_j, emb_r, emb_pl, emb_a,
                       w_fc1, b_fc1, w_fc2, b_fc2, out);
}